// Round 1
// baseline (194.883 us; speedup 1.0000x reference)
//
#include <hip/hip_runtime.h>
#include <hip/hip_bf16.h>
#include <stdint.h>

typedef __attribute__((ext_vector_type(8))) short short8;
typedef __attribute__((ext_vector_type(4))) float f32x4;
typedef unsigned short u16;
typedef unsigned int u32;

// B=2, H=16, L=2048, Dh=64, Dm=1024, M=B*L=4096, K=1024

__device__ __forceinline__ u16 bf16rne(float f) {
  u32 u = __builtin_bit_cast(u32, f);
  u += 0x7FFFu + ((u >> 16) & 1u);
  return (u16)(u >> 16);
}

__device__ __forceinline__ void gl_lds16(const u16* g, u16* l) {
  __builtin_amdgcn_global_load_lds((const __attribute__((address_space(1))) void*)g,
                                   (__attribute__((address_space(3))) void*)l, 16, 0, 0);
}

// ---------------- cast / pack kernel ----------------
struct CastArgs {
  const float* src[7];
  u16* dst[7];
  int n4[7];  // ids 0..5: float4 count; id 6: element count
};

__global__ void cast_all(CastArgs a) {
  const int id = blockIdx.y;
  const float* __restrict__ s = a.src[id];
  u16* __restrict__ d = a.dst[id];
  const int stride = gridDim.x * blockDim.x;
  const int i0 = blockIdx.x * blockDim.x + threadIdx.x;
  if (id < 6) {
    const int n4 = a.n4[id];
    for (int i = i0; i < n4; i += stride) {
      float4 v = ((const float4*)s)[i];
      u32 lo = (u32)bf16rne(v.x) | ((u32)bf16rne(v.y) << 16);
      u32 hi = (u32)bf16rne(v.z) | ((u32)bf16rne(v.w) << 16);
      ((uint2*)d)[i] = make_uint2(lo, hi);
    }
  } else {
    // W_O permute: dst[n][h*64+dd] = src[n][dd*16+h]
    const int n = a.n4[6];
    for (int i = i0; i < n; i += stride) {
      int row = i >> 10, c = i & 1023;
      int hh = c >> 6, dd = c & 63;
      d[i] = bf16rne(s[(row << 10) + dd * 16 + hh]);
    }
  }
}

// ---------------- GEMM: C[4096,1024] = A[4096,1024] * W[1024,1024]^T (bf16, fp32 acc) ----------
// EPI 0: scatter bf16 to [B][H][L][64]   (Q/K heads)
// EPI 1: scatter bf16 to [B][H][64][L]   (V transposed)
// EPI 2: plain fp32 row-major [4096][1024]
// AHEADS: A is [B][H][L][64] (k' = h*64+d), else flat [4096][1024]
template<int AHEADS>
__device__ __forceinline__ void gemm_body(const u16* __restrict__ A, const u16* __restrict__ Bw,
                                          void* __restrict__ Cd, int epi) {
  const int bn = blockIdx.x * 128, bm = blockIdx.y * 128;
  const int tid = threadIdx.x, lane = tid & 63, w = tid >> 6;
  const int wr = w >> 1, wc = w & 1;
  __shared__ __align__(16) u16 As[128 * 64];
  __shared__ __align__(16) u16 Bs[128 * 64];
  f32x4 acc[4][4];
#pragma unroll
  for (int m = 0; m < 4; ++m)
#pragma unroll
    for (int n = 0; n < 4; ++n) acc[m][n] = (f32x4){0.f, 0.f, 0.f, 0.f};

  for (int kt = 0; kt < 16; ++kt) {
#pragma unroll
    for (int i = 0; i < 4; ++i) {
      int c = tid + i * 256;
      int row = c >> 3, kc = c & 7;
      int swz = (kc ^ (row & 7)) << 3;
      const u16* srcA;
      if (AHEADS) {
        int bA = bm >> 11;
        int lrow = (bm & 2047) + row;
        srcA = A + ((size_t)(bA * 16 + kt) * 2048 + lrow) * 64 + swz;
      } else {
        srcA = A + (size_t)(bm + row) * 1024 + kt * 64 + swz;
      }
      gl_lds16(srcA, &As[c * 8]);
      const u16* srcB = Bw + (size_t)(bn + row) * 1024 + kt * 64 + swz;
      gl_lds16(srcB, &Bs[c * 8]);
    }
    __syncthreads();
#pragma unroll
    for (int ks = 0; ks < 2; ++ks) {
      const int ck = ks * 4 + (lane >> 4);
      short8 af[4], bfr[4];
#pragma unroll
      for (int m = 0; m < 4; ++m) {
        int r = wr * 64 + m * 16 + (lane & 15);
        af[m] = *(const short8*)&As[(r * 8 + (ck ^ (r & 7))) * 8];
      }
#pragma unroll
      for (int n = 0; n < 4; ++n) {
        int r = wc * 64 + n * 16 + (lane & 15);
        bfr[n] = *(const short8*)&Bs[(r * 8 + (ck ^ (r & 7))) * 8];
      }
#pragma unroll
      for (int m = 0; m < 4; ++m)
#pragma unroll
        for (int n = 0; n < 4; ++n)
          acc[m][n] = __builtin_amdgcn_mfma_f32_16x16x32_bf16(af[m], bfr[n], acc[m][n], 0, 0, 0);
    }
    __syncthreads();
  }

  const int lrow4 = (lane >> 4) << 2;
  const int h = lane & 15;
  if (epi == 0) {
    u16* D = (u16*)Cd;
    const int dbase = (bn + wc * 64) >> 4;
#pragma unroll
    for (int m = 0; m < 4; ++m)
#pragma unroll
      for (int i = 0; i < 4; ++i) {
        int R = bm + wr * 64 + m * 16 + lrow4 + i;
        int b = R >> 11, l = R & 2047;
        u32 lo = (u32)bf16rne(acc[m][0][i]) | ((u32)bf16rne(acc[m][1][i]) << 16);
        u32 hi = (u32)bf16rne(acc[m][2][i]) | ((u32)bf16rne(acc[m][3][i]) << 16);
        size_t addr = ((size_t)((b * 16 + h) * 2048 + l)) * 64 + dbase;
        *(uint2*)(D + addr) = make_uint2(lo, hi);
      }
  } else if (epi == 1) {
    u16* D = (u16*)Cd;
    const int dbase = (bn + wc * 64) >> 4;
    const int b = bm >> 11;
#pragma unroll
    for (int m = 0; m < 4; ++m) {
      int l0 = (bm & 2047) + wr * 64 + m * 16 + lrow4;
#pragma unroll
      for (int n = 0; n < 4; ++n) {
        int d = dbase + n;
        u32 lo = (u32)bf16rne(acc[m][n][0]) | ((u32)bf16rne(acc[m][n][1]) << 16);
        u32 hi = (u32)bf16rne(acc[m][n][2]) | ((u32)bf16rne(acc[m][n][3]) << 16);
        size_t addr = ((size_t)((b * 16 + h) * 64 + d)) * 2048 + l0;
        *(uint2*)(D + addr) = make_uint2(lo, hi);
      }
    }
  } else {
    float* D = (float*)Cd;
#pragma unroll
    for (int m = 0; m < 4; ++m)
#pragma unroll
      for (int i = 0; i < 4; ++i) {
        int R = bm + wr * 64 + m * 16 + lrow4 + i;
        size_t base = (size_t)R * 1024 + bn + wc * 64 + (lane & 15);
#pragma unroll
        for (int n = 0; n < 4; ++n) D[base + n * 16] = acc[m][n][i];
      }
  }
}

struct ProjArgs { const u16* A[3]; const u16* W[3]; u16* D[3]; };

__global__ __launch_bounds__(256, 2) void gemm_proj(ProjArgs pa) {
  const int z = blockIdx.z;
  gemm_body<0>(pa.A[z], pa.W[z], pa.D[z], z == 2 ? 1 : 0);
}

__global__ __launch_bounds__(256, 2) void gemm_oproj(const u16* __restrict__ A,
                                                     const u16* __restrict__ W,
                                                     float* __restrict__ C) {
  gemm_body<1>(A, W, C, 2);
}

// ---------------- flash attention ----------------
// Qh,Kh: [B][H][L][64] bf16 ; Vt: [B][H][64][L] bf16 ; Oh out: [B][H][L][64] bf16
__global__ __launch_bounds__(256, 2) void attn_kernel(const u16* __restrict__ Qh,
                                                      const u16* __restrict__ Kh,
                                                      const u16* __restrict__ Vt,
                                                      u16* __restrict__ Oh) {
  const int qt = blockIdx.x;          // 0..15 (q tile of 128 rows)
  const int hh = blockIdx.y, b = blockIdx.z;
  const int tid = threadIdx.x, lane = tid & 63, w = tid >> 6;
  __shared__ __align__(16) u16 Qs[128 * 64];
  __shared__ __align__(16) u16 Ks[128 * 64];
  __shared__ __align__(16) u16 Vs[64 * 128];
  __shared__ __align__(16) u16 Ps[128 * 128];

  const size_t hb = (size_t)(b * 16 + hh);
  const u16* Qg = Qh + hb * (2048 * 64);
  const u16* Kg = Kh + hb * (2048 * 64);
  const u16* Vg = Vt + hb * (64 * 2048);

  // stage Q tile once
#pragma unroll
  for (int i = 0; i < 4; ++i) {
    int c = tid + i * 256;
    int row = c >> 3, kc = c & 7;
    gl_lds16(Qg + (size_t)(qt * 128 + row) * 64 + ((kc ^ (row & 7)) << 3), &Qs[c * 8]);
  }

  f32x4 oacc[2][4];
  float mrow[2][4], lrow[2][4];
#pragma unroll
  for (int mf = 0; mf < 2; ++mf)
#pragma unroll
    for (int i = 0; i < 4; ++i) {
      mrow[mf][i] = -1e30f;
      lrow[mf][i] = 0.f;
#pragma unroll
      for (int df = 0; df < 4; ++df)
        if (i == 0) oacc[mf][df] = (f32x4){0.f, 0.f, 0.f, 0.f};
    }

  const float sl2e = 0.125f * 1.44269504088896f;  // 1/sqrt(64) * log2(e)

  for (int t = 0; t < 16; ++t) {
    // stage K rows [t*128, +128) and V cols [t*128, +128)
#pragma unroll
    for (int i = 0; i < 4; ++i) {
      int c = tid + i * 256;
      int row = c >> 3, kc = c & 7;
      gl_lds16(Kg + (size_t)(t * 128 + row) * 64 + ((kc ^ (row & 7)) << 3), &Ks[c * 8]);
      int dv = c >> 4, jc = c & 15;
      gl_lds16(Vg + (size_t)dv * 2048 + t * 128 + ((jc ^ (dv & 7)) << 3), &Vs[c * 8]);
    }
    __syncthreads();

    // S = Q K^T for this wave's 32 rows
    f32x4 sacc[2][8];
#pragma unroll
    for (int mf = 0; mf < 2; ++mf)
#pragma unroll
      for (int n = 0; n < 8; ++n) sacc[mf][n] = (f32x4){0.f, 0.f, 0.f, 0.f};
#pragma unroll
    for (int ks = 0; ks < 2; ++ks) {
      const int ck = ks * 4 + (lane >> 4);
      short8 af[2];
#pragma unroll
      for (int mf = 0; mf < 2; ++mf) {
        int r = w * 32 + mf * 16 + (lane & 15);
        af[mf] = *(const short8*)&Qs[(r * 8 + (ck ^ (r & 7))) * 8];
      }
#pragma unroll
      for (int n = 0; n < 8; ++n) {
        int rj = n * 16 + (lane & 15);
        short8 bfr = *(const short8*)&Ks[(rj * 8 + (ck ^ (rj & 7))) * 8];
#pragma unroll
        for (int mf = 0; mf < 2; ++mf)
          sacc[mf][n] = __builtin_amdgcn_mfma_f32_16x16x32_bf16(af[mf], bfr, sacc[mf][n], 0, 0, 0);
      }
    }

    // online softmax (fp32), write P (bf16) to swizzled LDS
#pragma unroll
    for (int mf = 0; mf < 2; ++mf) {
      float mx[4], al[4], rs[4];
#pragma unroll
      for (int i = 0; i < 4; ++i) {
        float v = sacc[mf][0][i];
#pragma unroll
        for (int n = 1; n < 8; ++n) v = fmaxf(v, sacc[mf][n][i]);
        mx[i] = v;
      }
#pragma unroll
      for (int off = 1; off < 16; off <<= 1)
#pragma unroll
        for (int i = 0; i < 4; ++i) mx[i] = fmaxf(mx[i], __shfl_xor(mx[i], off, 64));
#pragma unroll
      for (int i = 0; i < 4; ++i) {
        float Mn = fmaxf(mrow[mf][i], mx[i]);
        al[i] = exp2f((mrow[mf][i] - Mn) * sl2e);
        mrow[mf][i] = Mn;
        rs[i] = 0.f;
      }
      const int rbase = w * 32 + mf * 16 + ((lane >> 4) << 2);
#pragma unroll
      for (int n = 0; n < 8; ++n) {
        const int cc = n * 16 + (lane & 15);
#pragma unroll
        for (int i = 0; i < 4; ++i) {
          float p = exp2f((sacc[mf][n][i] - mrow[mf][i]) * sl2e);
          rs[i] += p;
          const int r = rbase + i;
          Ps[r * 128 + (((cc >> 3) ^ (r & 7)) << 3) + (cc & 7)] = bf16rne(p);
        }
      }
#pragma unroll
      for (int off = 1; off < 16; off <<= 1)
#pragma unroll
        for (int i = 0; i < 4; ++i) rs[i] += __shfl_xor(rs[i], off, 64);
#pragma unroll
      for (int i = 0; i < 4; ++i) {
        lrow[mf][i] = lrow[mf][i] * al[i] + rs[i];
#pragma unroll
        for (int df = 0; df < 4; ++df) oacc[mf][df][i] *= al[i];
      }
    }

    // O += P * V   (each wave reads only its own 32 P-rows -> no barrier needed)
#pragma unroll
    for (int ks = 0; ks < 4; ++ks) {
      const int ck = ks * 4 + (lane >> 4);
      short8 pa[2];
#pragma unroll
      for (int mf = 0; mf < 2; ++mf) {
        int r = w * 32 + mf * 16 + (lane & 15);
        pa[mf] = *(const short8*)&Ps[(r * 16 + (ck ^ (r & 7))) * 8];
      }
#pragma unroll
      for (int df = 0; df < 4; ++df) {
        int dv = df * 16 + (lane & 15);
        short8 vb = *(const short8*)&Vs[(dv * 16 + (ck ^ (dv & 7))) * 8];
#pragma unroll
        for (int mf = 0; mf < 2; ++mf)
          oacc[mf][df] = __builtin_amdgcn_mfma_f32_16x16x32_bf16(pa[mf], vb, oacc[mf][df], 0, 0, 0);
      }
    }
    __syncthreads();  // protect Ks/Vs before next staging
  }

  // epilogue: Oh[b][h][l][d]
  const size_t obase = hb * (size_t)(2048 * 64);
#pragma unroll
  for (int mf = 0; mf < 2; ++mf)
#pragma unroll
    for (int i = 0; i < 4; ++i) {
      float inv = 1.f / lrow[mf][i];
      int R = qt * 128 + w * 32 + mf * 16 + ((lane >> 4) << 2) + i;
#pragma unroll
      for (int df = 0; df < 4; ++df)
        Oh[obase + (size_t)R * 64 + df * 16 + (lane & 15)] = bf16rne(oacc[mf][df][i] * inv);
    }
}

// ---------------- launch ----------------
extern "C" void kernel_launch(void* const* d_in, const int* in_sizes, int n_in,
                              void* d_out, int out_size, void* d_ws, size_t ws_size,
                              hipStream_t stream) {
  const float* q = (const float*)d_in[0];
  const float* k = (const float*)d_in[1];
  const float* v = (const float*)d_in[2];
  const float* WQ = (const float*)d_in[3];
  const float* WK = (const float*)d_in[4];
  const float* WV = (const float*)d_in[5];
  const float* WO = (const float*)d_in[6];
  float* out = (float*)d_out;
  char* ws = (char*)d_ws;
  const size_t MB = 1024 * 1024;
  if (ws_size < 64 * MB) return;  // need 64MB scratch

  u16* qb  = (u16*)(ws + 0 * MB);
  u16* kb  = (u16*)(ws + 8 * MB);
  u16* vb  = (u16*)(ws + 16 * MB);
  u16* WQb = (u16*)(ws + 24 * MB);
  u16* WKb = (u16*)(ws + 26 * MB);
  u16* WVb = (u16*)(ws + 28 * MB);
  u16* WOt = (u16*)(ws + 30 * MB);
  u16* Qh  = (u16*)(ws + 32 * MB);
  u16* Kh  = (u16*)(ws + 40 * MB);
  u16* Vt  = (u16*)(ws + 48 * MB);
  u16* Ohd = (u16*)(ws + 56 * MB);

  CastArgs ca;
  ca.src[0] = q;  ca.dst[0] = qb;  ca.n4[0] = (4096 * 1024) / 4;
  ca.src[1] = k;  ca.dst[1] = kb;  ca.n4[1] = (4096 * 1024) / 4;
  ca.src[2] = v;  ca.dst[2] = vb;  ca.n4[2] = (4096 * 1024) / 4;
  ca.src[3] = WQ; ca.dst[3] = WQb; ca.n4[3] = (1024 * 1024) / 4;
  ca.src[4] = WK; ca.dst[4] = WKb; ca.n4[4] = (1024 * 1024) / 4;
  ca.src[5] = WV; ca.dst[5] = WVb; ca.n4[5] = (1024 * 1024) / 4;
  ca.src[6] = WO; ca.dst[6] = WOt; ca.n4[6] = 1024 * 1024;
  cast_all<<<dim3(256, 7), 256, 0, stream>>>(ca);

  ProjArgs pa;
  pa.A[0] = qb; pa.W[0] = WQb; pa.D[0] = Qh;
  pa.A[1] = kb; pa.W[1] = WKb; pa.D[1] = Kh;
  pa.A[2] = vb; pa.W[2] = WVb; pa.D[2] = Vt;
  gemm_proj<<<dim3(8, 32, 3), 256, 0, stream>>>(pa);

  attn_kernel<<<dim3(16, 16, 2), 256, 0, stream>>>(Qh, Kh, Vt, Ohd);

  gemm_oproj<<<dim3(8, 32), 256, 0, stream>>>(Ohd, WOt, out);
}

// Round 2
// 158.075 us; speedup vs baseline: 1.2328x; 1.2328x over previous
//
#include <hip/hip_runtime.h>
#include <hip/hip_bf16.h>
#include <stdint.h>

typedef __attribute__((ext_vector_type(8))) short short8;
typedef __attribute__((ext_vector_type(4))) float f32x4;
typedef __attribute__((ext_vector_type(16))) float f32x16;
typedef __attribute__((ext_vector_type(2))) int int2v;
typedef unsigned short u16;
typedef unsigned int u32;

// B=2, H=16, L=2048, Dh=64, Dm=1024, M=B*L=4096, K=1024

__device__ __forceinline__ u16 bf16rne(float f) {
  u32 u = __builtin_bit_cast(u32, f);
  u += 0x7FFFu + ((u >> 16) & 1u);
  return (u16)(u >> 16);
}

__device__ __forceinline__ u32 cvtpk(float lo, float hi) {
  u32 r;
  asm("v_cvt_pk_bf16_f32 %0, %1, %2" : "=v"(r) : "v"(lo), "v"(hi));
  return r;
}

__device__ __forceinline__ void gl_lds16(const u16* g, u16* l) {
  __builtin_amdgcn_global_load_lds((const __attribute__((address_space(1))) void*)g,
                                   (__attribute__((address_space(3))) void*)l, 16, 0, 0);
}

// ---------------- cast / pack kernel ----------------
struct CastArgs {
  const float* src[7];
  u16* dst[7];
  int n4[7];
  float scale[7];
};

__global__ void cast_all(CastArgs a) {
  const int id = blockIdx.y;
  const float* __restrict__ s = a.src[id];
  u16* __restrict__ d = a.dst[id];
  const float sc = a.scale[id];
  const int stride = gridDim.x * blockDim.x;
  const int i0 = blockIdx.x * blockDim.x + threadIdx.x;
  if (id < 6) {
    const int n4 = a.n4[id];
    for (int i = i0; i < n4; i += stride) {
      float4 v = ((const float4*)s)[i];
      u32 lo = (u32)bf16rne(v.x * sc) | ((u32)bf16rne(v.y * sc) << 16);
      u32 hi = (u32)bf16rne(v.z * sc) | ((u32)bf16rne(v.w * sc) << 16);
      ((uint2*)d)[i] = make_uint2(lo, hi);
    }
  } else {
    // W_O permute: dst[n][h*64+dd] = src[n][dd*16+h]
    const int n = a.n4[6];
    for (int i = i0; i < n; i += stride) {
      int row = i >> 10, c = i & 1023;
      int hh = c >> 6, dd = c & 63;
      d[i] = bf16rne(s[(row << 10) + dd * 16 + hh]);
    }
  }
}

// ---------------- GEMM: C[4096,1024] = A[4096,1024] * W[1024,1024]^T (bf16, fp32 acc) ----------
template<int AHEADS>
__device__ __forceinline__ void gemm_body(const u16* __restrict__ A, const u16* __restrict__ Bw,
                                          void* __restrict__ Cd, int epi) {
  const int bn = blockIdx.x * 128, bm = blockIdx.y * 128;
  const int tid = threadIdx.x, lane = tid & 63, w = tid >> 6;
  const int wr = w >> 1, wc = w & 1;
  __shared__ __align__(16) u16 As[128 * 64];
  __shared__ __align__(16) u16 Bs[128 * 64];
  f32x4 acc[4][4];
#pragma unroll
  for (int m = 0; m < 4; ++m)
#pragma unroll
    for (int n = 0; n < 4; ++n) acc[m][n] = (f32x4){0.f, 0.f, 0.f, 0.f};

  for (int kt = 0; kt < 16; ++kt) {
#pragma unroll
    for (int i = 0; i < 4; ++i) {
      int c = tid + i * 256;
      int row = c >> 3, kc = c & 7;
      int swz = (kc ^ (row & 7)) << 3;
      const u16* srcA;
      if (AHEADS) {
        int bA = bm >> 11;
        int lrow = (bm & 2047) + row;
        srcA = A + ((size_t)(bA * 16 + kt) * 2048 + lrow) * 64 + swz;
      } else {
        srcA = A + (size_t)(bm + row) * 1024 + kt * 64 + swz;
      }
      gl_lds16(srcA, &As[c * 8]);
      const u16* srcB = Bw + (size_t)(bn + row) * 1024 + kt * 64 + swz;
      gl_lds16(srcB, &Bs[c * 8]);
    }
    __syncthreads();
#pragma unroll
    for (int ks = 0; ks < 2; ++ks) {
      const int ck = ks * 4 + (lane >> 4);
      short8 af[4], bfr[4];
#pragma unroll
      for (int m = 0; m < 4; ++m) {
        int r = wr * 64 + m * 16 + (lane & 15);
        af[m] = *(const short8*)&As[(r * 8 + (ck ^ (r & 7))) * 8];
      }
#pragma unroll
      for (int n = 0; n < 4; ++n) {
        int r = wc * 64 + n * 16 + (lane & 15);
        bfr[n] = *(const short8*)&Bs[(r * 8 + (ck ^ (r & 7))) * 8];
      }
#pragma unroll
      for (int m = 0; m < 4; ++m)
#pragma unroll
        for (int n = 0; n < 4; ++n)
          acc[m][n] = __builtin_amdgcn_mfma_f32_16x16x32_bf16(af[m], bfr[n], acc[m][n], 0, 0, 0);
    }
    __syncthreads();
  }

  const int lrow4 = (lane >> 4) << 2;
  const int h = lane & 15;
  if (epi == 0) {
    u16* D = (u16*)Cd;
    const int dbase = (bn + wc * 64) >> 4;
#pragma unroll
    for (int m = 0; m < 4; ++m)
#pragma unroll
      for (int i = 0; i < 4; ++i) {
        int R = bm + wr * 64 + m * 16 + lrow4 + i;
        int b = R >> 11, l = R & 2047;
        u32 lo = (u32)bf16rne(acc[m][0][i]) | ((u32)bf16rne(acc[m][1][i]) << 16);
        u32 hi = (u32)bf16rne(acc[m][2][i]) | ((u32)bf16rne(acc[m][3][i]) << 16);
        size_t addr = ((size_t)((b * 16 + h) * 2048 + l)) * 64 + dbase;
        *(uint2*)(D + addr) = make_uint2(lo, hi);
      }
  } else if (epi == 1) {
    u16* D = (u16*)Cd;
    const int dbase = (bn + wc * 64) >> 4;
    const int b = bm >> 11;
#pragma unroll
    for (int m = 0; m < 4; ++m) {
      int l0 = (bm & 2047) + wr * 64 + m * 16 + lrow4;
#pragma unroll
      for (int n = 0; n < 4; ++n) {
        int d = dbase + n;
        u32 lo = (u32)bf16rne(acc[m][n][0]) | ((u32)bf16rne(acc[m][n][1]) << 16);
        u32 hi = (u32)bf16rne(acc[m][n][2]) | ((u32)bf16rne(acc[m][n][3]) << 16);
        size_t addr = ((size_t)((b * 16 + h) * 64 + d)) * 2048 + l0;
        *(uint2*)(D + addr) = make_uint2(lo, hi);
      }
    }
  } else {
    float* D = (float*)Cd;
#pragma unroll
    for (int m = 0; m < 4; ++m)
#pragma unroll
      for (int i = 0; i < 4; ++i) {
        int R = bm + wr * 64 + m * 16 + lrow4 + i;
        size_t base = (size_t)R * 1024 + bn + wc * 64 + (lane & 15);
#pragma unroll
        for (int n = 0; n < 4; ++n) D[base + n * 16] = acc[m][n][i];
      }
  }
}

struct ProjArgs { const u16* A[3]; const u16* W[3]; u16* D[3]; };

__global__ __launch_bounds__(256, 2) void gemm_proj(ProjArgs pa) {
  const int z = blockIdx.z;
  gemm_body<0>(pa.A[z], pa.W[z], pa.D[z], z == 2 ? 1 : 0);
}

__global__ __launch_bounds__(256, 2) void gemm_oproj(const u16* __restrict__ A,
                                                     const u16* __restrict__ W,
                                                     float* __restrict__ C) {
  gemm_body<1>(A, W, C, 2);
}

// ---------------- flash attention (8-warp, 32x32 swapped-operand) ----------------
// Qh,Kh: [B][H][L][64] bf16 (Q pre-scaled by 0.125*log2e via W_Q) ; Vt: [B][H][64][L] bf16
// Oh out: [B][H][L][64] bf16
// Per warp: 32 q-rows. S^T = mfma(K, Q^T): lane owns q = lane&31.
// O^T = mfma(V^T, P^T): lane owns q = lane&31 -> softmax + rescale all in-lane.
__global__ __launch_bounds__(512, 2) void attn_kernel(const u16* __restrict__ Qh,
                                                      const u16* __restrict__ Kh,
                                                      const u16* __restrict__ Vt,
                                                      u16* __restrict__ Oh) {
  const int qt = blockIdx.x, hh = blockIdx.y, b = blockIdx.z;
  const int tid = threadIdx.x, lane = tid & 63, w = tid >> 6;
  const int l31 = lane & 31, hi = lane >> 5;
  __shared__ __align__(16) u16 Ks[2][64 * 64];
  __shared__ __align__(16) u16 Vs[2][64 * 64];

  const size_t hb = (size_t)(b * 16 + hh);
  const u16* Kg = Kh + hb * (size_t)(2048 * 64);
  const u16* Vg = Vt + hb * (size_t)(64 * 2048);
  const u16* Qg = Qh + hb * (size_t)(2048 * 64);

  // Q fragments in registers: lane holds Q[qrow][ks*16 + hi*8 + e]
  const int qrow = qt * 256 + w * 32 + l31;
  short8 qf[4];
#pragma unroll
  for (int ks = 0; ks < 4; ++ks)
    qf[ks] = *(const short8*)(Qg + (size_t)qrow * 64 + ks * 16 + hi * 8);

  // staging: 512 threads, 1x16B per buffer each
  const int srow = tid >> 3, skc = tid & 7;
  const int ssw = (skc ^ (srow & 7)) << 3;

  f32x16 oacc0 = {}, oacc1 = {};
  float mrow = -1e30f, lrow = 0.f;

  // prologue
  gl_lds16(Kg + (size_t)srow * 64 + ssw, &Ks[0][tid * 8]);
  gl_lds16(Vg + (size_t)srow * 2048 + ssw, &Vs[0][tid * 8]);
  __syncthreads();

  int buf = 0;
  for (int t = 0; t < 32; ++t) {
    if (t < 31) {
      const int kv0 = (t + 1) * 64;
      gl_lds16(Kg + (size_t)(kv0 + srow) * 64 + ssw, &Ks[buf ^ 1][tid * 8]);
      gl_lds16(Vg + (size_t)srow * 2048 + kv0 + ssw, &Vs[buf ^ 1][tid * 8]);
    }

    // ---- S^T = K * Q^T  (two 32-kv sub-tiles) ----
    f32x16 s0 = {}, s1 = {};
#pragma unroll
    for (int ks = 0; ks < 4; ++ks) {
      const int ck = 2 * ks + hi;
      const int r0 = l31, r1 = 32 + l31;
      short8 k0 = *(const short8*)&Ks[buf][(r0 * 8 + (ck ^ (r0 & 7))) * 8];
      short8 k1 = *(const short8*)&Ks[buf][(r1 * 8 + (ck ^ (r1 & 7))) * 8];
      s0 = __builtin_amdgcn_mfma_f32_32x32x16_bf16(k0, qf[ks], s0, 0, 0, 0);
      s1 = __builtin_amdgcn_mfma_f32_32x32x16_bf16(k1, qf[ks], s1, 0, 0, 0);
    }

    // ---- online softmax, fully in-lane (q = lane&31) ----
    f32x16 m01 = __builtin_elementwise_max(s0, s1);
    float t8[8];
#pragma unroll
    for (int i = 0; i < 8; ++i) t8[i] = fmaxf(m01[i], m01[i + 8]);
#pragma unroll
    for (int i = 0; i < 4; ++i) t8[i] = fmaxf(t8[i], t8[i + 4]);
    float tmax = fmaxf(fmaxf(t8[0], t8[1]), fmaxf(t8[2], t8[3]));
    {
      int2v pr = __builtin_amdgcn_permlane32_swap(__builtin_bit_cast(int, tmax),
                                                  __builtin_bit_cast(int, tmax), false, false);
      tmax = fmaxf(__builtin_bit_cast(float, pr[0]), __builtin_bit_cast(float, pr[1]));
    }
    if (__any(tmax > mrow + 8.0f)) {  // defer-max: rare after tile 0
      float mn = fmaxf(mrow, tmax);
      float al = exp2f(mrow - mn);
      mrow = mn;
      lrow *= al;
#pragma unroll
      for (int i = 0; i < 16; ++i) { oacc0[i] *= al; oacc1[i] *= al; }
    }
    f32x16 p0, p1;
#pragma unroll
    for (int i = 0; i < 16; ++i) { p0[i] = exp2f(s0[i] - mrow); p1[i] = exp2f(s1[i] - mrow); }
    {
      f32x16 a01 = p0 + p1;
      float r8[8];
#pragma unroll
      for (int i = 0; i < 8; ++i) r8[i] = a01[i] + a01[i + 8];
#pragma unroll
      for (int i = 0; i < 4; ++i) r8[i] += r8[i + 4];
      float rsum = (r8[0] + r8[1]) + (r8[2] + r8[3]);
      int2v pr = __builtin_amdgcn_permlane32_swap(__builtin_bit_cast(int, rsum),
                                                  __builtin_bit_cast(int, rsum), false, false);
      lrow += __builtin_bit_cast(float, pr[0]) + __builtin_bit_cast(float, pr[1]);
    }

    // ---- O^T += V^T * P^T : P fragments built in-register (cvt_pk + permlane32_swap) ----
#pragma unroll
    for (int st = 0; st < 2; ++st) {
#pragma unroll
      for (int s = 0; s < 2; ++s) {
        float pe0, pe1, pe2, pe3, pe4, pe5, pe6, pe7;
        if (st == 0) {
          pe0 = p0[8 * s + 0]; pe1 = p0[8 * s + 1]; pe2 = p0[8 * s + 2]; pe3 = p0[8 * s + 3];
          pe4 = p0[8 * s + 4]; pe5 = p0[8 * s + 5]; pe6 = p0[8 * s + 6]; pe7 = p0[8 * s + 7];
        } else {
          pe0 = p1[8 * s + 0]; pe1 = p1[8 * s + 1]; pe2 = p1[8 * s + 2]; pe3 = p1[8 * s + 3];
          pe4 = p1[8 * s + 4]; pe5 = p1[8 * s + 5]; pe6 = p1[8 * s + 6]; pe7 = p1[8 * s + 7];
        }
        u32 c0 = cvtpk(pe0, pe1), c1 = cvtpk(pe2, pe3);
        u32 c2 = cvtpk(pe4, pe5), c3 = cvtpk(pe6, pe7);
        int2v w02 = __builtin_amdgcn_permlane32_swap((int)c0, (int)c2, false, false);
        int2v w13 = __builtin_amdgcn_permlane32_swap((int)c1, (int)c3, false, false);
        union { u32 wu[4]; short8 v; } un;
        un.wu[0] = (u32)w02[0]; un.wu[1] = (u32)w13[0];
        un.wu[2] = (u32)w02[1]; un.wu[3] = (u32)w13[1];
        const short8 pa = un.v;
        const int cb = st * 4 + s * 2 + hi;
        {
          const int row = l31;
          short8 va = *(const short8*)&Vs[buf][(row * 8 + (cb ^ (row & 7))) * 8];
          oacc0 = __builtin_amdgcn_mfma_f32_32x32x16_bf16(va, pa, oacc0, 0, 0, 0);
        }
        {
          const int row = 32 + l31;
          short8 va = *(const short8*)&Vs[buf][(row * 8 + (cb ^ (row & 7))) * 8];
          oacc1 = __builtin_amdgcn_mfma_f32_32x32x16_bf16(va, pa, oacc1, 0, 0, 0);
        }
      }
    }
    __syncthreads();
    buf ^= 1;
  }

  // ---- epilogue: lane owns q-row `qrow`; O^T vals at d = dblk*32 + crow(r,hi) ----
  const float inv = 1.0f / lrow;
  u16* Og = Oh + hb * (size_t)(2048 * 64) + (size_t)qrow * 64;
#pragma unroll
  for (int dblk = 0; dblk < 2; ++dblk) {
#pragma unroll
    for (int r = 0; r < 16; r += 2) {
      const int d = dblk * 32 + (r & 3) + 8 * (r >> 2) + 4 * hi;
      float v0 = (dblk ? oacc1[r] : oacc0[r]) * inv;
      float v1 = (dblk ? oacc1[r + 1] : oacc0[r + 1]) * inv;
      *(u32*)(Og + d) = cvtpk(v0, v1);
    }
  }
}

// ---------------- launch ----------------
extern "C" void kernel_launch(void* const* d_in, const int* in_sizes, int n_in,
                              void* d_out, int out_size, void* d_ws, size_t ws_size,
                              hipStream_t stream) {
  const float* q = (const float*)d_in[0];
  const float* k = (const float*)d_in[1];
  const float* v = (const float*)d_in[2];
  const float* WQ = (const float*)d_in[3];
  const float* WK = (const float*)d_in[4];
  const float* WV = (const float*)d_in[5];
  const float* WO = (const float*)d_in[6];
  float* out = (float*)d_out;
  char* ws = (char*)d_ws;
  const size_t MB = 1024 * 1024;
  if (ws_size < 64 * MB) return;

  u16* qb  = (u16*)(ws + 0 * MB);
  u16* kb  = (u16*)(ws + 8 * MB);
  u16* vb  = (u16*)(ws + 16 * MB);
  u16* WQb = (u16*)(ws + 24 * MB);
  u16* WKb = (u16*)(ws + 26 * MB);
  u16* WVb = (u16*)(ws + 28 * MB);
  u16* WOt = (u16*)(ws + 30 * MB);
  u16* Qh  = (u16*)(ws + 32 * MB);
  u16* Kh  = (u16*)(ws + 40 * MB);
  u16* Vt  = (u16*)(ws + 48 * MB);
  u16* Ohd = (u16*)(ws + 56 * MB);

  CastArgs ca;
  ca.src[0] = q;  ca.dst[0] = qb;  ca.n4[0] = (4096 * 1024) / 4;
  ca.src[1] = k;  ca.dst[1] = kb;  ca.n4[1] = (4096 * 1024) / 4;
  ca.src[2] = v;  ca.dst[2] = vb;  ca.n4[2] = (4096 * 1024) / 4;
  ca.src[3] = WQ; ca.dst[3] = WQb; ca.n4[3] = (1024 * 1024) / 4;
  ca.src[4] = WK; ca.dst[4] = WKb; ca.n4[4] = (1024 * 1024) / 4;
  ca.src[5] = WV; ca.dst[5] = WVb; ca.n4[5] = (1024 * 1024) / 4;
  ca.src[6] = WO; ca.dst[6] = WOt; ca.n4[6] = 1024 * 1024;
  for (int i = 0; i < 7; ++i) ca.scale[i] = 1.0f;
  ca.scale[3] = 0.125f * 1.44269504088896f;  // fold 1/sqrt(64)*log2(e) into W_Q
  cast_all<<<dim3(256, 7), 256, 0, stream>>>(ca);

  ProjArgs pa;
  pa.A[0] = qb; pa.W[0] = WQb; pa.D[0] = Qh;
  pa.A[1] = kb; pa.W[1] = WKb; pa.D[1] = Kh;
  pa.A[2] = vb; pa.W[2] = WVb; pa.D[2] = Vt;
  gemm_proj<<<dim3(8, 32, 3), 256, 0, stream>>>(pa);

  attn_kernel<<<dim3(8, 16, 2), 512, 0, stream>>>(Qh, Kh, Vt, Ohd);

  gemm_oproj<<<dim3(8, 32), 256, 0, stream>>>(Ohd, WOt, out);
}